// Round 7
// baseline (353.644 us; speedup 1.0000x reference)
//
#include <hip/hip_runtime.h>

#define N_NODES 50000
#define N_EDGES 600000
#define DFEAT   128
#define SCAN_NB ((N_NODES + 255) / 256)   // 196 blocks

typedef __attribute__((ext_vector_type(8))) short short8;
typedef __attribute__((ext_vector_type(4))) float floatx4;

__device__ __forceinline__ unsigned short f2bf_rtne(float f) {
    unsigned b = __float_as_uint(f);
    return (unsigned short)((b + 0x7FFFu + ((b >> 16) & 1u)) >> 16);
}
__device__ __forceinline__ float bf2f(unsigned short u) {
    return __uint_as_float(((unsigned)u) << 16);
}

// ---------------- CSR build step 1: int histogram of dst ----------------
__global__ void sage_hist_kernel(const int* __restrict__ dst, int* __restrict__ cnt, int nE) {
    int e = blockIdx.x * blockDim.x + threadIdx.x;
    if (e < nE) atomicAdd(&cnt[dst[e]], 1);
}

// ---------------- CSR build step 2a: per-block sums ----------------
__global__ __launch_bounds__(256) void sage_bsum_kernel(
        const int* __restrict__ cnt, int* __restrict__ bsum, int n) {
    int i = blockIdx.x * 256 + threadIdx.x;
    int v = (i < n) ? cnt[i] : 0;
    #pragma unroll
    for (int off = 32; off > 0; off >>= 1) v += __shfl_down(v, off, 64);
    __shared__ int ws[4];
    if ((threadIdx.x & 63) == 0) ws[threadIdx.x >> 6] = v;
    __syncthreads();
    if (threadIdx.x == 0) bsum[blockIdx.x] = ws[0] + ws[1] + ws[2] + ws[3];
}

// ---------------- CSR build step 2b: exclusive scan of block sums ----------------
__global__ __launch_bounds__(256) void sage_bscan_kernel(int* __restrict__ bsum, int nb) {
    int t = threadIdx.x;
    int v = (t < nb) ? bsum[t] : 0;
    int lane = t & 63, wid = t >> 6;
    int incl = v;
    #pragma unroll
    for (int off = 1; off < 64; off <<= 1) {
        int y = __shfl_up(incl, off, 64);
        if (lane >= off) incl += y;
    }
    __shared__ int ws[4];
    if (lane == 63) ws[wid] = incl;
    __syncthreads();
    int wpre = 0;
    for (int w = 0; w < wid; w++) wpre += ws[w];
    if (t < nb) bsum[t] = wpre + incl - v;   // exclusive
}

// ---------------- CSR build step 2c: per-block scan + offset ----------------
__global__ __launch_bounds__(256) void sage_scan2_kernel(
        const int* __restrict__ cnt, const int* __restrict__ bscan,
        int* __restrict__ row_ptr, int* __restrict__ cursor,
        float* __restrict__ invdeg, int n) {
    int i = blockIdx.x * 256 + threadIdx.x;
    int v = (i < n) ? cnt[i] : 0;
    int lane = threadIdx.x & 63, wid = threadIdx.x >> 6;
    int incl = v;
    #pragma unroll
    for (int off = 1; off < 64; off <<= 1) {
        int y = __shfl_up(incl, off, 64);
        if (lane >= off) incl += y;
    }
    __shared__ int ws[4];
    if (lane == 63) ws[wid] = incl;
    __syncthreads();
    int wpre = 0;
    for (int w = 0; w < wid; w++) wpre += ws[w];
    int excl = bscan[blockIdx.x] + wpre + incl - v;
    if (i < n) {
        row_ptr[i] = excl;
        cursor[i]  = excl;
        invdeg[i]  = 1.0f / fmaxf((float)v, 1.0f);
    }
    if (i == n - 1) row_ptr[n] = excl + v;
}

// ---------------- CSR build step 3: fill sorted_src (ushort) via cursor ----------------
__global__ void sage_fill_kernel(const int* __restrict__ src, const int* __restrict__ dst,
                                 int* __restrict__ cursor,
                                 unsigned short* __restrict__ sorted_src, int nE) {
    int e = blockIdx.x * blockDim.x + threadIdx.x;
    if (e < nE) {
        int p = atomicAdd(&cursor[dst[e]], 1);
        sorted_src[p] = (unsigned short)src[e];
    }
}

// ---------------- x (fp32) -> 8 slice-separated bf16 tables ----------------
// hbs layout: slice s (16 feats) at hbs + s*N_NODES*16; row = 32B, slice-pure lines.
__global__ __launch_bounds__(256) void sage_x2slice_kernel(
        const float* __restrict__ x, unsigned short* __restrict__ hbs, int nNodes) {
    int idx = blockIdx.x * 256 + threadIdx.x;   // one thread per 8-feat group
    int node = idx >> 4;
    int g = idx & 15;
    if (node >= nNodes) return;
    const float* p = x + (long)node * DFEAT + g * 8;
    float4 v0 = *(const float4*)p;
    float4 v1 = *(const float4*)(p + 4);
    int s = g >> 1, half = g & 1;
    unsigned short* d = hbs + ((long)s * N_NODES + node) * 16 + half * 8;
    ushort4 o0, o1;
    o0.x = f2bf_rtne(v0.x); o0.y = f2bf_rtne(v0.y); o0.z = f2bf_rtne(v0.z); o0.w = f2bf_rtne(v0.w);
    o1.x = f2bf_rtne(v1.x); o1.y = f2bf_rtne(v1.y); o1.z = f2bf_rtne(v1.z); o1.w = f2bf_rtne(v1.w);
    *(ushort4*)d = o0;
    *(ushort4*)(d + 4) = o1;
}

// ---------------- pull-based mean aggregation from L2-resident slice tables --------
// Block b: slice s = b&7 (round-robin -> XCD s, 1.6MB table resident in XCD L2),
// nodes (b>>3)*32..+32. 8 threads per node, thread owns 2 feats (ushort2 load).
__global__ __launch_bounds__(256) void sage_gather_kernel(
        const unsigned short* __restrict__ hbs, const int* __restrict__ row_ptr,
        const unsigned short* __restrict__ sorted_src, const float* __restrict__ invdeg,
        float* __restrict__ mean, int nNodes)
{
    const int s = blockIdx.x & 7;
    const int node = (blockIdx.x >> 3) * 32 + (threadIdx.x >> 3);
    const int fp = threadIdx.x & 7;          // feat-pair within slice
    if (node >= nNodes) return;
    const ushort2* tab = (const ushort2*)(hbs + (long)s * N_NODES * 16);
    const int beg = row_ptr[node];
    const int end = row_ptr[node + 1];
    float a0 = 0.f, a1 = 0.f, a2 = 0.f, a3 = 0.f;
    float c0 = 0.f, c1 = 0.f, c2 = 0.f, c3 = 0.f;
    int e = beg;
    for (; e + 4 <= end; e += 4) {
        int s0 = sorted_src[e];
        int s1 = sorted_src[e + 1];
        int s2 = sorted_src[e + 2];
        int s3 = sorted_src[e + 3];
        ushort2 v0 = tab[s0 * 8 + fp];
        ushort2 v1 = tab[s1 * 8 + fp];
        ushort2 v2 = tab[s2 * 8 + fp];
        ushort2 v3 = tab[s3 * 8 + fp];
        a0 += bf2f(v0.x); c0 += bf2f(v0.y);
        a1 += bf2f(v1.x); c1 += bf2f(v1.y);
        a2 += bf2f(v2.x); c2 += bf2f(v2.y);
        a3 += bf2f(v3.x); c3 += bf2f(v3.y);
    }
    for (; e < end; e++) {
        ushort2 v = tab[sorted_src[e] * 8 + fp];
        a0 += bf2f(v.x); c0 += bf2f(v.y);
    }
    float sc = invdeg[node];
    float2 r = make_float2((a0 + a1 + a2 + a3) * sc, (c0 + c1 + c2 + c3) * sc);
    *(float2*)(mean + (long)node * DFEAT + s * 16 + fp * 2) = r;
}

// ---------------- W prep: split fp32 -> bf16 hi/lo, swizzle to MFMA B-frag order ----
__global__ __launch_bounds__(64) void sage_wprep_kernel(
        const float* __restrict__ Ws, const float* __restrict__ Wn,
        unsigned short* __restrict__ Whi, unsigned short* __restrict__ Wlo, int N) {
    int NT = N / 16;
    int fid = blockIdx.x;            // kt*NT + nt
    int kt = fid / NT, nt = fid % NT;
    int lane = threadIdx.x;
    int kbase = kt * 32 + (lane >> 4) * 8;
    int n = nt * 16 + (lane & 15);
    long base = ((long)fid * 64 + lane) * 8;
    #pragma unroll
    for (int j = 0; j < 8; j++) {
        int k = kbase + j;
        float w = (k < 128) ? Ws[k * N + n] : Wn[(k - 128) * N + n];
        unsigned b = __float_as_uint(w);
        unsigned hib = b & 0xFFFF0000u;
        float lo = w - __uint_as_float(hib);
        Whi[base + j] = (unsigned short)(b >> 16);
        Wlo[base + j] = (unsigned short)(__float_as_uint(lo) >> 16);
    }
}

// ---------------- MFMA bf16-split dual-matmul + bias + relu ----------------
// WB: also emits bf16 copy of output into the slice-separated table layout.
template<int NT, bool RELU, bool WB>
__global__ __launch_bounds__(64) void sage_mm_mfma_kernel(
        const float* __restrict__ h, const float* __restrict__ mean,
        const unsigned short* __restrict__ Whi, const unsigned short* __restrict__ Wlo,
        const float* __restrict__ bias, float* __restrict__ out,
        unsigned short* __restrict__ hbs_out, int M)
{
    constexpr int N = NT * 16;
    const int lane = threadIdx.x;
    const int q    = lane >> 4;      // quad 0..3
    const int l16  = lane & 15;
    const int rowbase = blockIdx.x * 32;

    floatx4 acc[2][NT];
    #pragma unroll
    for (int mt = 0; mt < 2; mt++)
        #pragma unroll
        for (int nt = 0; nt < NT; nt++)
            acc[mt][nt] = (floatx4){0.f, 0.f, 0.f, 0.f};

    int r0 = rowbase + l16;       if (r0 >= M) r0 = M - 1;
    int r1 = rowbase + 16 + l16;  if (r1 >= M) r1 = M - 1;

    #pragma unroll 2
    for (int kt = 0; kt < 8; kt++) {
        const float* srcb = (kt < 4) ? h : mean;
        const int koff = (kt & 3) * 32 + q * 8;

        union { short8 v; unsigned u[4]; } ahi[2], alo[2];
        #pragma unroll
        for (int mt = 0; mt < 2; mt++) {
            const float* p = srcb + (long)(mt == 0 ? r0 : r1) * DFEAT + koff;
            float4 x0 = *(const float4*)p;
            float4 x1 = *(const float4*)(p + 4);
            float xs[8] = {x0.x, x0.y, x0.z, x0.w, x1.x, x1.y, x1.z, x1.w};
            #pragma unroll
            for (int pr = 0; pr < 4; pr++) {
                unsigned b0 = __float_as_uint(xs[2 * pr]);
                unsigned b1 = __float_as_uint(xs[2 * pr + 1]);
                unsigned h0b = b0 & 0xFFFF0000u;
                unsigned h1b = b1 & 0xFFFF0000u;
                ahi[mt].u[pr] = (b0 >> 16) | h1b;
                float l0 = xs[2 * pr]     - __uint_as_float(h0b);
                float l1 = xs[2 * pr + 1] - __uint_as_float(h1b);
                alo[mt].u[pr] = (__float_as_uint(l0) >> 16) |
                                (__float_as_uint(l1) & 0xFFFF0000u);
            }
        }

        #pragma unroll
        for (int nt = 0; nt < NT; nt++) {
            long fb = ((long)(kt * NT + nt) * 64 + lane) * 8;
            short8 bhi = *(const short8*)(Whi + fb);
            short8 blo = *(const short8*)(Wlo + fb);
            #pragma unroll
            for (int mt = 0; mt < 2; mt++) {
                acc[mt][nt] = __builtin_amdgcn_mfma_f32_16x16x32_bf16(ahi[mt].v, bhi, acc[mt][nt], 0, 0, 0);
                acc[mt][nt] = __builtin_amdgcn_mfma_f32_16x16x32_bf16(alo[mt].v, bhi, acc[mt][nt], 0, 0, 0);
                acc[mt][nt] = __builtin_amdgcn_mfma_f32_16x16x32_bf16(ahi[mt].v, blo, acc[mt][nt], 0, 0, 0);
            }
        }
    }

    #pragma unroll
    for (int nt = 0; nt < NT; nt++) {
        float bv = bias[nt * 16 + l16];
        #pragma unroll
        for (int mt = 0; mt < 2; mt++) {
            #pragma unroll
            for (int reg = 0; reg < 4; reg++) {
                int grow = rowbase + mt * 16 + q * 4 + reg;
                if (grow < M) {
                    float v = acc[mt][nt][reg] + bv;
                    if (RELU) v = fmaxf(v, 0.f);
                    out[(long)grow * N + nt * 16 + l16] = v;
                    if (WB) hbs_out[((long)nt * N_NODES + grow) * 16 + l16] = f2bf_rtne(v);
                }
            }
        }
    }
}

extern "C" void kernel_launch(void* const* d_in, const int* in_sizes, int n_in,
                              void* d_out, int out_size, void* d_ws, size_t ws_size,
                              hipStream_t stream) {
    const float* x   = (const float*)d_in[0];
    const int*   ei  = (const int*)d_in[1];
    const float* Ws0 = (const float*)d_in[2];
    const float* Wn0 = (const float*)d_in[3];
    const float* b0  = (const float*)d_in[4];
    const float* Ws1 = (const float*)d_in[5];
    const float* Wn1 = (const float*)d_in[6];
    const float* b1  = (const float*)d_in[7];
    const float* Ws2 = (const float*)d_in[8];
    const float* Wn2 = (const float*)d_in[9];
    const float* b2  = (const float*)d_in[10];
    float* out = (float*)d_out;

    const int* src = ei;
    const int* dst = ei + N_EDGES;

    // ---- workspace layout ----
    char* ws = (char*)d_ws;
    float* invdeg     = (float*)ws;   ws += 50176 * 4;
    int*   cnt        = (int*)ws;     ws += 50176 * 4;
    int*   row_ptr    = (int*)ws;     ws += 50432 * 4;
    int*   cursor     = (int*)ws;     ws += 50432 * 4;
    int*   bsum       = (int*)ws;     ws += 256 * 4;
    unsigned short* sorted_src = (unsigned short*)ws; ws += 600064 * 2;
    unsigned short* Whi0 = (unsigned short*)ws; ws += 8 * 8 * 64 * 8 * 2;   // 64 KB
    unsigned short* Wlo0 = (unsigned short*)ws; ws += 8 * 8 * 64 * 8 * 2;
    unsigned short* Whi1 = (unsigned short*)ws; ws += 8 * 8 * 64 * 8 * 2;
    unsigned short* Wlo1 = (unsigned short*)ws; ws += 8 * 8 * 64 * 8 * 2;
    unsigned short* Whi2 = (unsigned short*)ws; ws += 8 * 4 * 64 * 8 * 2;   // 32 KB
    unsigned short* Wlo2 = (unsigned short*)ws; ws += 8 * 4 * 64 * 8 * 2;
    unsigned short* hbs = (unsigned short*)ws;  ws += (long)N_NODES * DFEAT * 2;  // 12.8 MB
    float* mean       = (float*)ws;   ws += (long)N_NODES * DFEAT * 4;
    float* h0         = (float*)ws;   ws += (long)N_NODES * DFEAT * 4;
    float* h1         = (float*)ws;

    // ---- CSR build ----
    hipMemsetAsync(cnt, 0, 50176 * sizeof(int), stream);
    sage_hist_kernel<<<(N_EDGES + 255) / 256, 256, 0, stream>>>(dst, cnt, N_EDGES);
    sage_bsum_kernel<<<SCAN_NB, 256, 0, stream>>>(cnt, bsum, N_NODES);
    sage_bscan_kernel<<<1, 256, 0, stream>>>(bsum, SCAN_NB);
    sage_scan2_kernel<<<SCAN_NB, 256, 0, stream>>>(cnt, bsum, row_ptr, cursor, invdeg, N_NODES);
    sage_fill_kernel<<<(N_EDGES + 255) / 256, 256, 0, stream>>>(
        src, dst, cursor, sorted_src, N_EDGES);

    // ---- weight prep + x -> bf16 slice tables ----
    sage_wprep_kernel<<<64, 64, 0, stream>>>(Ws0, Wn0, Whi0, Wlo0, 128);
    sage_wprep_kernel<<<64, 64, 0, stream>>>(Ws1, Wn1, Whi1, Wlo1, 128);
    sage_wprep_kernel<<<32, 64, 0, stream>>>(Ws2, Wn2, Whi2, Wlo2, 64);
    const int xs_blocks = (N_NODES * 16 + 255) / 256;
    sage_x2slice_kernel<<<xs_blocks, 256, 0, stream>>>(x, hbs, N_NODES);

    const int gather_blocks = 8 * ((N_NODES + 31) / 32);   // 12504
    const int mm_blocks = (N_NODES + 31) / 32;             // 1563 single-wave blocks

    // ---- layer 0 ----
    sage_gather_kernel<<<gather_blocks, 256, 0, stream>>>(
        hbs, row_ptr, sorted_src, invdeg, mean, N_NODES);
    sage_mm_mfma_kernel<8, true, true><<<mm_blocks, 64, 0, stream>>>(
        x, mean, Whi0, Wlo0, b0, h0, hbs, N_NODES);

    // ---- layer 1 ----
    sage_gather_kernel<<<gather_blocks, 256, 0, stream>>>(
        hbs, row_ptr, sorted_src, invdeg, mean, N_NODES);
    sage_mm_mfma_kernel<8, true, true><<<mm_blocks, 64, 0, stream>>>(
        h0, mean, Whi1, Wlo1, b1, h1, hbs, N_NODES);

    // ---- layer 2 ----
    sage_gather_kernel<<<gather_blocks, 256, 0, stream>>>(
        hbs, row_ptr, sorted_src, invdeg, mean, N_NODES);
    sage_mm_mfma_kernel<4, false, false><<<mm_blocks, 64, 0, stream>>>(
        h1, mean, Whi2, Wlo2, b2, out, nullptr, N_NODES);
}

// Round 8
// 343.931 us; speedup vs baseline: 1.0282x; 1.0282x over previous
//
#include <hip/hip_runtime.h>

#define N_NODES 50000
#define N_EDGES 600000
#define DFEAT   128
#define SCAN_NB ((N_NODES + 255) / 256)   // 196 blocks

typedef __attribute__((ext_vector_type(8))) short short8;
typedef __attribute__((ext_vector_type(4))) float floatx4;

__device__ __forceinline__ unsigned short f2bf_rtne(float f) {
    unsigned b = __float_as_uint(f);
    return (unsigned short)((b + 0x7FFFu + ((b >> 16) & 1u)) >> 16);
}
__device__ __forceinline__ float bf2f(unsigned short u) {
    return __uint_as_float(((unsigned)u) << 16);
}

// ---------------- CSR build step 1: int histogram of dst ----------------
__global__ void sage_hist_kernel(const int* __restrict__ dst, int* __restrict__ cnt, int nE) {
    int e = blockIdx.x * blockDim.x + threadIdx.x;
    if (e < nE) atomicAdd(&cnt[dst[e]], 1);
}

// ---------------- CSR build step 2a: per-block sums ----------------
__global__ __launch_bounds__(256) void sage_bsum_kernel(
        const int* __restrict__ cnt, int* __restrict__ bsum, int n) {
    int i = blockIdx.x * 256 + threadIdx.x;
    int v = (i < n) ? cnt[i] : 0;
    #pragma unroll
    for (int off = 32; off > 0; off >>= 1) v += __shfl_down(v, off, 64);
    __shared__ int ws[4];
    if ((threadIdx.x & 63) == 0) ws[threadIdx.x >> 6] = v;
    __syncthreads();
    if (threadIdx.x == 0) bsum[blockIdx.x] = ws[0] + ws[1] + ws[2] + ws[3];
}

// ---------------- CSR build step 2b: exclusive scan of block sums ----------------
__global__ __launch_bounds__(256) void sage_bscan_kernel(int* __restrict__ bsum, int nb) {
    int t = threadIdx.x;
    int v = (t < nb) ? bsum[t] : 0;
    int lane = t & 63, wid = t >> 6;
    int incl = v;
    #pragma unroll
    for (int off = 1; off < 64; off <<= 1) {
        int y = __shfl_up(incl, off, 64);
        if (lane >= off) incl += y;
    }
    __shared__ int ws[4];
    if (lane == 63) ws[wid] = incl;
    __syncthreads();
    int wpre = 0;
    for (int w = 0; w < wid; w++) wpre += ws[w];
    if (t < nb) bsum[t] = wpre + incl - v;   // exclusive
}

// ---------------- CSR build step 2c: per-block scan + offset ----------------
__global__ __launch_bounds__(256) void sage_scan2_kernel(
        const int* __restrict__ cnt, const int* __restrict__ bscan,
        int* __restrict__ row_ptr, int* __restrict__ cursor,
        float* __restrict__ invdeg, int n) {
    int i = blockIdx.x * 256 + threadIdx.x;
    int v = (i < n) ? cnt[i] : 0;
    int lane = threadIdx.x & 63, wid = threadIdx.x >> 6;
    int incl = v;
    #pragma unroll
    for (int off = 1; off < 64; off <<= 1) {
        int y = __shfl_up(incl, off, 64);
        if (lane >= off) incl += y;
    }
    __shared__ int ws[4];
    if (lane == 63) ws[wid] = incl;
    __syncthreads();
    int wpre = 0;
    for (int w = 0; w < wid; w++) wpre += ws[w];
    int excl = bscan[blockIdx.x] + wpre + incl - v;
    if (i < n) {
        row_ptr[i] = excl;
        cursor[i]  = excl;
        invdeg[i]  = 1.0f / fmaxf((float)v, 1.0f);
    }
    if (i == n - 1) row_ptr[n] = excl + v;
}

// ---------------- CSR build step 3: fill sorted_src (ushort) via cursor ----------------
__global__ void sage_fill_kernel(const int* __restrict__ src, const int* __restrict__ dst,
                                 int* __restrict__ cursor,
                                 unsigned short* __restrict__ sorted_src, int nE) {
    int e = blockIdx.x * blockDim.x + threadIdx.x;
    if (e < nE) {
        int p = atomicAdd(&cursor[dst[e]], 1);
        sorted_src[p] = (unsigned short)src[e];
    }
}

// ---------------- fp32 -> bf16 table conversion (RTNE), float4 vectorized ----------
__global__ __launch_bounds__(256) void sage_f2bf_kernel(
        const float* __restrict__ in, unsigned short* __restrict__ out, int n4) {
    int i = blockIdx.x * 256 + threadIdx.x;
    if (i < n4) {
        float4 v = ((const float4*)in)[i];
        ushort4 o;
        o.x = f2bf_rtne(v.x); o.y = f2bf_rtne(v.y);
        o.z = f2bf_rtne(v.z); o.w = f2bf_rtne(v.w);
        ((ushort4*)out)[i] = o;
    }
}

// ---------------- pull-based mean aggregation from bf16 table ----------------
// One wave per node; lane owns 2 features (ushort2 = 4B load, 256B coalesced/row).
// Output mean in bf16 (RTNE) — exact bf16 A-fragment for the mm mean path.
__global__ __launch_bounds__(256) void sage_gather_kernel(
        const ushort2* __restrict__ hb, const int* __restrict__ row_ptr,
        const unsigned short* __restrict__ sorted_src, const float* __restrict__ invdeg,
        unsigned short* __restrict__ mean_b, int nNodes)
{
    int node = blockIdx.x * 4 + (threadIdx.x >> 6);
    int lane = threadIdx.x & 63;
    if (node >= nNodes) return;
    const int beg = row_ptr[node];
    const int end = row_ptr[node + 1];
    float a0 = 0.f, a1 = 0.f, a2 = 0.f, a3 = 0.f;
    float c0 = 0.f, c1 = 0.f, c2 = 0.f, c3 = 0.f;
    int e = beg;
    for (; e + 4 <= end; e += 4) {
        int s0 = sorted_src[e];
        int s1 = sorted_src[e + 1];
        int s2 = sorted_src[e + 2];
        int s3 = sorted_src[e + 3];
        ushort2 v0 = hb[(long)s0 * 64 + lane];
        ushort2 v1 = hb[(long)s1 * 64 + lane];
        ushort2 v2 = hb[(long)s2 * 64 + lane];
        ushort2 v3 = hb[(long)s3 * 64 + lane];
        a0 += bf2f(v0.x); c0 += bf2f(v0.y);
        a1 += bf2f(v1.x); c1 += bf2f(v1.y);
        a2 += bf2f(v2.x); c2 += bf2f(v2.y);
        a3 += bf2f(v3.x); c3 += bf2f(v3.y);
    }
    for (; e < end; e++) {
        ushort2 v = hb[(long)sorted_src[e] * 64 + lane];
        a0 += bf2f(v.x); c0 += bf2f(v.y);
    }
    float s = invdeg[node];
    ushort2 r;
    r.x = f2bf_rtne((a0 + a1 + a2 + a3) * s);
    r.y = f2bf_rtne((c0 + c1 + c2 + c3) * s);
    ((ushort2*)(mean_b + (long)node * DFEAT))[lane] = r;
}

// ---------------- W prep (all 3 layers in one launch) ----------------
// Splits fp32 W into bf16 hi/lo, swizzled to MFMA B-frag order.
// blocks 0..63: layer0 (N=128), 64..127: layer1 (N=128), 128..159: layer2 (N=64).
__global__ __launch_bounds__(64) void sage_wprep_all_kernel(
        const float* __restrict__ Ws0, const float* __restrict__ Wn0,
        const float* __restrict__ Ws1, const float* __restrict__ Wn1,
        const float* __restrict__ Ws2, const float* __restrict__ Wn2,
        unsigned short* __restrict__ Whi0, unsigned short* __restrict__ Wlo0,
        unsigned short* __restrict__ Whi1, unsigned short* __restrict__ Wlo1,
        unsigned short* __restrict__ Whi2, unsigned short* __restrict__ Wlo2) {
    int b = blockIdx.x;
    const float *Ws, *Wn;
    unsigned short *Whi, *Wlo;
    int N, fid;
    if (b < 64)       { Ws = Ws0; Wn = Wn0; Whi = Whi0; Wlo = Wlo0; N = 128; fid = b; }
    else if (b < 128) { Ws = Ws1; Wn = Wn1; Whi = Whi1; Wlo = Wlo1; N = 128; fid = b - 64; }
    else              { Ws = Ws2; Wn = Wn2; Whi = Whi2; Wlo = Wlo2; N = 64;  fid = b - 128; }
    int NT = N / 16;
    int kt = fid / NT, nt = fid % NT;
    int lane = threadIdx.x;
    int kbase = kt * 32 + (lane >> 4) * 8;
    int n = nt * 16 + (lane & 15);
    long base = ((long)fid * 64 + lane) * 8;
    #pragma unroll
    for (int j = 0; j < 8; j++) {
        int k = kbase + j;
        float w = (k < 128) ? Ws[k * N + n] : Wn[(k - 128) * N + n];
        unsigned bb = __float_as_uint(w);
        unsigned hib = bb & 0xFFFF0000u;
        float lo = w - __uint_as_float(hib);
        Whi[base + j] = (unsigned short)(bb >> 16);
        Wlo[base + j] = (unsigned short)(__float_as_uint(lo) >> 16);
    }
}

// ---------------- MFMA dual-matmul + bias + relu ----------------
// Self path (kt 0..3): fp32 h, 3-term bf16 split (Ahi*Whi + Alo*Whi + Ahi*Wlo).
// Mean path (kt 4..7): bf16 mean read directly as A-frag, exact -> 2 MFMAs
//   (Am*Whi + Am*Wlo).
// WB: also emits bf16 copy of output for the next layer's gather.
template<int NT, bool RELU, bool WB>
__global__ __launch_bounds__(64) void sage_mm_mfma_kernel(
        const float* __restrict__ h, const unsigned short* __restrict__ mean_b,
        const unsigned short* __restrict__ Whi, const unsigned short* __restrict__ Wlo,
        const float* __restrict__ bias, float* __restrict__ out,
        unsigned short* __restrict__ hb_out, int M)
{
    constexpr int N = NT * 16;
    const int lane = threadIdx.x;
    const int q    = lane >> 4;      // quad 0..3
    const int l16  = lane & 15;
    const int rowbase = blockIdx.x * 32;

    floatx4 acc[2][NT];
    #pragma unroll
    for (int mt = 0; mt < 2; mt++)
        #pragma unroll
        for (int nt = 0; nt < NT; nt++)
            acc[mt][nt] = (floatx4){0.f, 0.f, 0.f, 0.f};

    int r0 = rowbase + l16;       if (r0 >= M) r0 = M - 1;
    int r1 = rowbase + 16 + l16;  if (r1 >= M) r1 = M - 1;
    const int rr[2] = {r0, r1};

    #pragma unroll
    for (int kt = 0; kt < 8; kt++) {
        const int koff = (kt & 3) * 32 + q * 8;

        if (kt < 4) {
            // ---- self path: fp32 h with in-register hi/lo split ----
            union { short8 v; unsigned u[4]; } ahi[2], alo[2];
            #pragma unroll
            for (int mt = 0; mt < 2; mt++) {
                const float* p = h + (long)rr[mt] * DFEAT + koff;
                float4 x0 = *(const float4*)p;
                float4 x1 = *(const float4*)(p + 4);
                float xs[8] = {x0.x, x0.y, x0.z, x0.w, x1.x, x1.y, x1.z, x1.w};
                #pragma unroll
                for (int pr = 0; pr < 4; pr++) {
                    unsigned b0 = __float_as_uint(xs[2 * pr]);
                    unsigned b1 = __float_as_uint(xs[2 * pr + 1]);
                    unsigned h0b = b0 & 0xFFFF0000u;
                    unsigned h1b = b1 & 0xFFFF0000u;
                    ahi[mt].u[pr] = (b0 >> 16) | h1b;
                    float l0 = xs[2 * pr]     - __uint_as_float(h0b);
                    float l1 = xs[2 * pr + 1] - __uint_as_float(h1b);
                    alo[mt].u[pr] = (__float_as_uint(l0) >> 16) |
                                    (__float_as_uint(l1) & 0xFFFF0000u);
                }
            }
            #pragma unroll
            for (int nt = 0; nt < NT; nt++) {
                long fb = ((long)(kt * NT + nt) * 64 + lane) * 8;
                short8 bhi = *(const short8*)(Whi + fb);
                short8 blo = *(const short8*)(Wlo + fb);
                #pragma unroll
                for (int mt = 0; mt < 2; mt++) {
                    acc[mt][nt] = __builtin_amdgcn_mfma_f32_16x16x32_bf16(ahi[mt].v, bhi, acc[mt][nt], 0, 0, 0);
                    acc[mt][nt] = __builtin_amdgcn_mfma_f32_16x16x32_bf16(alo[mt].v, bhi, acc[mt][nt], 0, 0, 0);
                    acc[mt][nt] = __builtin_amdgcn_mfma_f32_16x16x32_bf16(ahi[mt].v, blo, acc[mt][nt], 0, 0, 0);
                }
            }
        } else {
            // ---- mean path: bf16 mean is the A-frag directly (exact) ----
            short8 am[2];
            #pragma unroll
            for (int mt = 0; mt < 2; mt++)
                am[mt] = *(const short8*)(mean_b + (long)rr[mt] * DFEAT + koff);
            #pragma unroll
            for (int nt = 0; nt < NT; nt++) {
                long fb = ((long)(kt * NT + nt) * 64 + lane) * 8;
                short8 bhi = *(const short8*)(Whi + fb);
                short8 blo = *(const short8*)(Wlo + fb);
                #pragma unroll
                for (int mt = 0; mt < 2; mt++) {
                    acc[mt][nt] = __builtin_amdgcn_mfma_f32_16x16x32_bf16(am[mt], bhi, acc[mt][nt], 0, 0, 0);
                    acc[mt][nt] = __builtin_amdgcn_mfma_f32_16x16x32_bf16(am[mt], blo, acc[mt][nt], 0, 0, 0);
                }
            }
        }
    }

    #pragma unroll
    for (int nt = 0; nt < NT; nt++) {
        float bv = bias[nt * 16 + l16];
        #pragma unroll
        for (int mt = 0; mt < 2; mt++) {
            #pragma unroll
            for (int reg = 0; reg < 4; reg++) {
                int grow = rowbase + mt * 16 + q * 4 + reg;
                if (grow < M) {
                    float v = acc[mt][nt][reg] + bv;
                    if (RELU) v = fmaxf(v, 0.f);
                    long idx = (long)grow * N + nt * 16 + l16;
                    out[idx] = v;
                    if (WB) hb_out[idx] = f2bf_rtne(v);
                }
            }
        }
    }
}

extern "C" void kernel_launch(void* const* d_in, const int* in_sizes, int n_in,
                              void* d_out, int out_size, void* d_ws, size_t ws_size,
                              hipStream_t stream) {
    const float* x   = (const float*)d_in[0];
    const int*   ei  = (const int*)d_in[1];
    const float* Ws0 = (const float*)d_in[2];
    const float* Wn0 = (const float*)d_in[3];
    const float* b0  = (const float*)d_in[4];
    const float* Ws1 = (const float*)d_in[5];
    const float* Wn1 = (const float*)d_in[6];
    const float* b1  = (const float*)d_in[7];
    const float* Ws2 = (const float*)d_in[8];
    const float* Wn2 = (const float*)d_in[9];
    const float* b2  = (const float*)d_in[10];
    float* out = (float*)d_out;

    const int* src = ei;
    const int* dst = ei + N_EDGES;

    // ---- workspace layout ----
    char* ws = (char*)d_ws;
    float* invdeg     = (float*)ws;   ws += 50176 * 4;
    int*   cnt        = (int*)ws;     ws += 50176 * 4;
    int*   row_ptr    = (int*)ws;     ws += 50432 * 4;
    int*   cursor     = (int*)ws;     ws += 50432 * 4;
    int*   bsum       = (int*)ws;     ws += 256 * 4;
    unsigned short* sorted_src = (unsigned short*)ws; ws += 600064 * 2;
    unsigned short* Whi0 = (unsigned short*)ws; ws += 8 * 8 * 64 * 8 * 2;   // 64 KB
    unsigned short* Wlo0 = (unsigned short*)ws; ws += 8 * 8 * 64 * 8 * 2;
    unsigned short* Whi1 = (unsigned short*)ws; ws += 8 * 8 * 64 * 8 * 2;
    unsigned short* Wlo1 = (unsigned short*)ws; ws += 8 * 8 * 64 * 8 * 2;
    unsigned short* Whi2 = (unsigned short*)ws; ws += 8 * 4 * 64 * 8 * 2;   // 32 KB
    unsigned short* Wlo2 = (unsigned short*)ws; ws += 8 * 4 * 64 * 8 * 2;
    unsigned short* hb  = (unsigned short*)ws;  ws += (long)N_NODES * DFEAT * 2;  // 12.8 MB
    unsigned short* mean_b = (unsigned short*)ws; ws += (long)N_NODES * DFEAT * 2; // 12.8 MB
    float* h0         = (float*)ws;   ws += (long)N_NODES * DFEAT * 4;
    float* h1         = (float*)ws;

    // ---- CSR build ----
    hipMemsetAsync(cnt, 0, 50176 * sizeof(int), stream);
    sage_hist_kernel<<<(N_EDGES + 255) / 256, 256, 0, stream>>>(dst, cnt, N_EDGES);
    sage_bsum_kernel<<<SCAN_NB, 256, 0, stream>>>(cnt, bsum, N_NODES);
    sage_bscan_kernel<<<1, 256, 0, stream>>>(bsum, SCAN_NB);
    sage_scan2_kernel<<<SCAN_NB, 256, 0, stream>>>(cnt, bsum, row_ptr, cursor, invdeg, N_NODES);
    sage_fill_kernel<<<(N_EDGES + 255) / 256, 256, 0, stream>>>(
        src, dst, cursor, sorted_src, N_EDGES);

    // ---- weight prep (single launch) + x -> bf16 table ----
    sage_wprep_all_kernel<<<160, 64, 0, stream>>>(
        Ws0, Wn0, Ws1, Wn1, Ws2, Wn2, Whi0, Wlo0, Whi1, Wlo1, Whi2, Wlo2);
    const int n4 = N_NODES * DFEAT / 4;
    sage_f2bf_kernel<<<(n4 + 255) / 256, 256, 0, stream>>>(x, hb, n4);

    const int gather_blocks = (N_NODES + 3) / 4;   // wave per node
    const int mm_blocks = (N_NODES + 31) / 32;     // 1563 single-wave blocks

    // ---- layer 0 ----
    sage_gather_kernel<<<gather_blocks, 256, 0, stream>>>(
        (const ushort2*)hb, row_ptr, sorted_src, invdeg, mean_b, N_NODES);
    sage_mm_mfma_kernel<8, true, true><<<mm_blocks, 64, 0, stream>>>(
        x, mean_b, Whi0, Wlo0, b0, h0, hb, N_NODES);

    // ---- layer 1 ----
    sage_gather_kernel<<<gather_blocks, 256, 0, stream>>>(
        (const ushort2*)hb, row_ptr, sorted_src, invdeg, mean_b, N_NODES);
    sage_mm_mfma_kernel<8, true, true><<<mm_blocks, 64, 0, stream>>>(
        h0, mean_b, Whi1, Wlo1, b1, h1, hb, N_NODES);

    // ---- layer 2 ----
    sage_gather_kernel<<<gather_blocks, 256, 0, stream>>>(
        (const ushort2*)hb, row_ptr, sorted_src, invdeg, mean_b, N_NODES);
    sage_mm_mfma_kernel<4, false, false><<<mm_blocks, 64, 0, stream>>>(
        h1, mean_b, Whi2, Wlo2, b2, out, nullptr, N_NODES);
}